// Round 1
// baseline (991.803 us; speedup 1.0000x reference)
//
#include <hip/hip_runtime.h>
#include <hip/hip_bf16.h>
#include <cstdint>
#include <cstddef>

typedef __hip_bfloat16 bf16;
typedef __bf16 bf16x8 __attribute__((ext_vector_type(8)));
typedef float f32x4 __attribute__((ext_vector_type(4)));

#define S_D 30
#define C_D 16
#define N_R 46        // S_D + C_D rows per batch
#define H_D 768
#define EPS_F 1e-5f

// ------------------------------------------------------------------
// prep: normalize adjacency matrices once (they are layer-invariant)
// ------------------------------------------------------------------
__global__ __launch_bounds__(64) void prep_norm_k(
    const float* __restrict__ a_cur, const float* __restrict__ a_slot,
    const float* __restrict__ a_last, const float* __restrict__ a_dom,
    float* __restrict__ Acr, float* __restrict__ Acc, float* __restrict__ Asl,
    float* __restrict__ Alr, float* __restrict__ Alc, float* __restrict__ Adm)
{
  int b = blockIdx.x, t = threadIdx.x;
  const float* ac  = a_cur  + b*S_D*C_D;
  const float* as_ = a_slot + b*S_D*S_D;
  const float* al  = a_last + b*S_D*C_D;
  const float* ad  = a_dom  + b*S_D*S_D;
  if (t < S_D) {
    float s = 0; for (int c=0;c<C_D;c++) s += ac[t*C_D+c];
    float inv = 1.f/(s+EPS_F);
    for (int c=0;c<C_D;c++) Acr[b*S_D*C_D + t*C_D+c] = ac[t*C_D+c]*inv;
    s = 0; for (int c=0;c<C_D;c++) s += al[t*C_D+c];
    inv = 1.f/(s+EPS_F);
    for (int c=0;c<C_D;c++) Alr[b*S_D*C_D + t*C_D+c] = al[t*C_D+c]*inv;
    s = 0; for (int j=0;j<S_D;j++) s += as_[t*S_D+j];
    inv = 1.f/(s+EPS_F);
    for (int j=0;j<S_D;j++) Asl[b*S_D*S_D + t*S_D+j] = as_[t*S_D+j]*inv;
    s = 0; for (int j=0;j<S_D;j++) s += ad[t*S_D+j];
    inv = 1.f/(s+EPS_F);
    for (int j=0;j<S_D;j++) Adm[b*S_D*S_D + t*S_D+j] = ad[t*S_D+j]*inv;
  } else if (t < S_D + C_D) {
    int c = t - S_D;
    float s = 0; for (int j=0;j<S_D;j++) s += ac[j*C_D+c];
    float inv = 1.f/(s+EPS_F);
    for (int j=0;j<S_D;j++) Acc[b*S_D*C_D + j*C_D+c] = ac[j*C_D+c]*inv;
    s = 0; for (int j=0;j<S_D;j++) s += al[j*C_D+c];
    inv = 1.f/(s+EPS_F);
    for (int j=0;j<S_D;j++) Alc[b*S_D*C_D + j*C_D+c] = al[j*C_D+c]*inv;
  }
}

// ------------------------------------------------------------------
// prep: bf16 transposed weight concats + folded biases
// Wcat  [768n x 3840k] : [W_s; W_r0; W_r1; W_r2; W_r3] transposed
// Wg    [768n x 1536k] : W_g transposed
// Wcat2 [768n x 2304k] : [W_s; W_r0; W_r2] transposed (layer-2 cls-only)
// ------------------------------------------------------------------
__global__ __launch_bounds__(256) void prep_weights_k(
    const float* __restrict__ W_r, const float* __restrict__ b_r,
    const float* __restrict__ W_s, const float* __restrict__ b_s,
    const float* __restrict__ W_g,
    bf16* __restrict__ Wcat, bf16* __restrict__ Wg, bf16* __restrict__ Wcat2,
    float* __restrict__ bslot, float* __restrict__ bcls)
{
  int id = blockIdx.x*256 + threadIdx.x;
  const int n1 = 768*3840, n2 = 768*1536, n3 = 768*2304;
  if (id < n1) {
    int n = id / 3840, k = id % 3840, seg = k / 768, kk = k % 768;
    float w = (seg == 0) ? W_s[kk*768 + n] : W_r[((size_t)(seg-1)*768 + kk)*768 + n];
    Wcat[id] = __float2bfloat16(w);
  } else if (id < n1 + n2) {
    int j = id - n1; int n = j / 1536, k = j % 1536;
    Wg[j] = __float2bfloat16(W_g[(size_t)k*768 + n]);
  } else if (id < n1 + n2 + n3) {
    int j = id - n1 - n2; int n = j / 2304, k = j % 2304, seg = k / 768, kk = k % 768;
    float w = (seg == 0) ? W_s[kk*768 + n]
            : (seg == 1 ? W_r[(size_t)kk*768 + n] : W_r[((size_t)2*768 + kk)*768 + n]);
    Wcat2[j] = __float2bfloat16(w);
  } else if (id < n1 + n2 + n3 + 768) {
    int n = id - n1 - n2 - n3;
    bslot[n] = b_s[n] + b_r[n] + b_r[768+n] + b_r[2*768+n] + b_r[3*768+n];
    bcls[n]  = b_s[n] + b_r[n] + b_r[2*768+n];
  }
}

// ------------------------------------------------------------------
// prep: state init (X f32, seg0 of Xcat bf16, right half of Gin bf16)
// ------------------------------------------------------------------
__global__ __launch_bounds__(256) void prep_state_k(
    const float* __restrict__ slots, const float* __restrict__ cls,
    float* __restrict__ X, bf16* __restrict__ Xcat, bf16* __restrict__ Gin,
    int b0, int nrows)
{
  int id = blockIdx.x*256 + threadIdx.x;
  if (id >= nrows*768) return;
  int h = id % 768, lr = id / 768, lb = lr / N_R, r = lr % N_R;
  int b = b0 + lb;
  float v = (r < S_D) ? slots[((size_t)b*S_D + r)*768 + h]
                      : cls[((size_t)b*C_D + (r - S_D))*768 + h];
  X[id] = v;
  bf16 bv = __float2bfloat16(v);
  Xcat[(size_t)lr*3840 + h] = bv;
  Gin[(size_t)lr*1536 + 768 + h] = bv;
}

// ------------------------------------------------------------------
// layer-1 aggregation: fill Xcat segments 1..4 with A_norm @ X
// block = one batch, 768 threads (one per h). Coefs are wave-uniform
// global loads -> s_load; x column lives in registers.
// ------------------------------------------------------------------
__global__ __launch_bounds__(768) void aggregate1_k(
    const float* __restrict__ X, bf16* __restrict__ Xcat,
    const float* __restrict__ Acr, const float* __restrict__ Acc,
    const float* __restrict__ Asl, const float* __restrict__ Alr,
    const float* __restrict__ Alc, const float* __restrict__ Adm, int b0)
{
  int lb = blockIdx.x, b = b0 + lb, h = threadIdx.x;
  const float* Xb = X + (size_t)lb*N_R*768;
  float xs[S_D], xc[C_D];
  #pragma unroll
  for (int s = 0; s < S_D; ++s) xs[s] = Xb[s*768 + h];
  #pragma unroll
  for (int c = 0; c < C_D; ++c) xc[c] = Xb[(S_D + c)*768 + h];
  const float* acr  = Acr + b*480;
  const float* acc_ = Acc + b*480;
  const float* alr  = Alr + b*480;
  const float* alc  = Alc + b*480;
  const float* asl  = Asl + b*900;
  const float* adm  = Adm + b*900;
  bf16* Xb16 = Xcat + (size_t)lb*N_R*3840 + h;
  const bf16 z = __float2bfloat16(0.f);
  #pragma unroll 1
  for (int s = 0; s < S_D; ++s) {
    float a1 = 0, a2 = 0, a3 = 0, a4 = 0;
    #pragma unroll
    for (int c = 0; c < C_D; ++c) { a1 += acr[s*C_D + c]*xc[c]; a3 += alr[s*C_D + c]*xc[c]; }
    #pragma unroll
    for (int t = 0; t < S_D; ++t) { a2 += asl[s*S_D + t]*xs[t]; a4 += adm[s*S_D + t]*xs[t]; }
    bf16* row = Xb16 + (size_t)s*3840;
    row[768]  = __float2bfloat16(a1);
    row[1536] = __float2bfloat16(a2);
    row[2304] = __float2bfloat16(a3);
    row[3072] = __float2bfloat16(a4);
  }
  #pragma unroll 1
  for (int c = 0; c < C_D; ++c) {
    float a1 = 0, a3 = 0;
    #pragma unroll
    for (int s = 0; s < S_D; ++s) { a1 += acc_[s*C_D + c]*xs[s]; a3 += alc[s*C_D + c]*xs[s]; }
    bf16* row = Xb16 + (size_t)(S_D + c)*3840;
    row[768]  = __float2bfloat16(a1);
    row[1536] = z;
    row[2304] = __float2bfloat16(a3);
    row[3072] = z;
  }
}

// ------------------------------------------------------------------
// layer-2 aggregation (cls rows only): Xcat2 [chunkB*16, 2304]
// segs: [cls | Acc^T@slots | Alc^T@slots]; also Gin2 right half = cls
// ------------------------------------------------------------------
__global__ __launch_bounds__(768) void aggregate2_k(
    const float* __restrict__ X, bf16* __restrict__ Xcat2, bf16* __restrict__ Gin2,
    const float* __restrict__ Acc, const float* __restrict__ Alc, int b0)
{
  int lb = blockIdx.x, b = b0 + lb, h = threadIdx.x;
  const float* Xb = X + (size_t)lb*N_R*768;
  float xs[S_D];
  #pragma unroll
  for (int s = 0; s < S_D; ++s) xs[s] = Xb[s*768 + h];
  const float* acc_ = Acc + b*480;
  const float* alc  = Alc + b*480;
  #pragma unroll 1
  for (int c = 0; c < C_D; ++c) {
    float v = Xb[(S_D + c)*768 + h];
    float a1 = 0, a3 = 0;
    #pragma unroll
    for (int s = 0; s < S_D; ++s) { a1 += acc_[s*C_D + c]*xs[s]; a3 += alc[s*C_D + c]*xs[s]; }
    size_t r2 = (size_t)lb*C_D + c;
    bf16* row = Xcat2 + r2*2304 + h;
    row[0]    = __float2bfloat16(v);
    row[768]  = __float2bfloat16(a1);
    row[1536] = __float2bfloat16(a3);
    Gin2[r2*1536 + 768 + h] = __float2bfloat16(v);
  }
}

// ------------------------------------------------------------------
// MFMA GEMM: C[M x 768] = A[M x K] @ Bt[768 x K]^T, 128x128 tile, BK=64
// EPI 1: proj layer1  -> U f32 + Gin[:, :768] bf16, bias by row type
// EPI 2: gate layer1  -> sigmoid + residual update -> X
// EPI 3: proj layer2  -> U + Gin left, bias_cls
// EPI 4: gate layer2  -> update scattered into X cls rows
// ------------------------------------------------------------------
template<int K, int EPI>
__global__ __launch_bounds__(256) void gemm_k(
    const bf16* __restrict__ A, const bf16* __restrict__ Bt,
    float* __restrict__ U, bf16* __restrict__ Gin,
    const float* __restrict__ bias_slot, const float* __restrict__ bias_cls,
    const float* __restrict__ bg, float* __restrict__ X)
{
  __shared__ __align__(16) bf16 As[128*64];
  __shared__ __align__(16) bf16 Bs[128*64];
  const int tid  = threadIdx.x;
  const int lane = tid & 63;
  const int wave = tid >> 6;
  const int wm = wave >> 1, wn = wave & 1;
  const int bm = blockIdx.x / 6, bn = blockIdx.x % 6;

  const bf16* Ag = A  + (size_t)bm*128*K + (size_t)(tid>>3)*K + (tid&7)*8;
  const bf16* Bg = Bt + (size_t)bn*128*K + (size_t)(tid>>3)*K + (tid&7)*8;
  bf16* Asw = &As[(wave*8)*64];
  bf16* Bsw = &Bs[(wave*8)*64];

  f32x4 acc[4][4] = {};

  for (int kt = 0; kt < K; kt += 64) {
    #pragma unroll
    for (int p = 0; p < 4; ++p) {
      __builtin_amdgcn_global_load_lds(
        (const __attribute__((address_space(1))) void*)(Ag + (size_t)(p*32)*K + kt),
        (__attribute__((address_space(3))) void*)(Asw + p*32*64), 16, 0, 0);
      __builtin_amdgcn_global_load_lds(
        (const __attribute__((address_space(1))) void*)(Bg + (size_t)(p*32)*K + kt),
        (__attribute__((address_space(3))) void*)(Bsw + p*32*64), 16, 0, 0);
    }
    __syncthreads();
    #pragma unroll
    for (int ks = 0; ks < 64; ks += 32) {
      bf16x8 af[4], bfv[4];
      #pragma unroll
      for (int i = 0; i < 4; ++i) {
        int m = wm*64 + i*16 + (lane & 15);
        af[i]  = *(const bf16x8*)&As[m*64 + ks + ((lane>>4)<<3)];
        int n = wn*64 + i*16 + (lane & 15);
        bfv[i] = *(const bf16x8*)&Bs[n*64 + ks + ((lane>>4)<<3)];
      }
      #pragma unroll
      for (int i = 0; i < 4; ++i)
        #pragma unroll
        for (int j = 0; j < 4; ++j)
          acc[i][j] = __builtin_amdgcn_mfma_f32_16x16x32_bf16(af[i], bfv[j], acc[i][j], 0, 0, 0);
    }
    __syncthreads();
  }

  const int rbase = bm*128 + wm*64 + ((lane>>4)<<2);
  const int cbase = bn*128 + wn*64 + (lane & 15);
  #pragma unroll
  for (int i = 0; i < 4; ++i) {
    #pragma unroll
    for (int j = 0; j < 4; ++j) {
      const int col = cbase + j*16;
      #pragma unroll
      for (int r = 0; r < 4; ++r) {
        const int row = rbase + i*16 + r;
        float v = acc[i][j][r];
        if constexpr (EPI == 1) {
          int rb = row % N_R;
          v += (rb < S_D ? bias_slot[col] : bias_cls[col]);
          U[(size_t)row*H_D + col] = v;
          Gin[(size_t)row*1536 + col] = __float2bfloat16(v);
        } else if constexpr (EPI == 3) {
          v += bias_cls[col];
          U[(size_t)row*H_D + col] = v;
          Gin[(size_t)row*1536 + col] = __float2bfloat16(v);
        } else if constexpr (EPI == 2) {
          v += bg[col];
          float g = 1.f/(1.f + __expf(-v));
          float u  = U[(size_t)row*H_D + col];
          float xo = X[(size_t)row*H_D + col];
          X[(size_t)row*H_D + col] = fmaxf(u, 0.f)*g + xo*(1.f - g);
        } else { // EPI == 4
          v += bg[col];
          float g = 1.f/(1.f + __expf(-v));
          float u = U[(size_t)row*H_D + col];
          int xrow = (row >> 4)*N_R + S_D + (row & 15);
          float xo = X[(size_t)xrow*H_D + col];
          X[(size_t)xrow*H_D + col] = fmaxf(u, 0.f)*g + xo*(1.f - g);
        }
      }
    }
  }
}

// ------------------------------------------------------------------
__global__ __launch_bounds__(256) void out_copy_k(
    const float* __restrict__ X, float* __restrict__ out, int b0, int chunkB)
{
  int id = blockIdx.x*256 + threadIdx.x;
  if (id >= chunkB*15*768) return;
  int h = id % 768, t = id / 768, lb = t / 15, c = t % 15;
  out[((size_t)(b0+lb)*15 + c)*768 + h] = X[((size_t)lb*N_R + S_D + 1 + c)*768 + h];
}

// ------------------------------------------------------------------
extern "C" void kernel_launch(void* const* d_in, const int* in_sizes, int n_in,
                              void* d_out, int out_size, void* d_ws, size_t ws_size,
                              hipStream_t stream)
{
  const float* slots  = (const float*)d_in[0];
  const float* cls    = (const float*)d_in[1];
  const float* a_cur  = (const float*)d_in[2];
  const float* a_slot = (const float*)d_in[3];
  const float* a_last = (const float*)d_in[4];
  const float* a_dom  = (const float*)d_in[5];
  const float* W_r    = (const float*)d_in[6];
  const float* b_r    = (const float*)d_in[7];
  const float* W_s    = (const float*)d_in[8];
  const float* b_s    = (const float*)d_in[9];
  const float* W_g    = (const float*)d_in[10];
  const float* b_g    = (const float*)d_in[11];
  float* out = (float*)d_out;

  char* base = (char*)d_ws;
  size_t off = 0;
  auto alloc = [&](size_t bytes) -> void* {
    void* r = base + off;
    off = (off + bytes + 255) & ~(size_t)255;
    return r;
  };

  float* Acr = (float*)alloc((size_t)512*480*4);
  float* Acc = (float*)alloc((size_t)512*480*4);
  float* Alr = (float*)alloc((size_t)512*480*4);
  float* Alc = (float*)alloc((size_t)512*480*4);
  float* Asl = (float*)alloc((size_t)512*900*4);
  float* Adm = (float*)alloc((size_t)512*900*4);
  bf16* Wcat  = (bf16*)alloc((size_t)768*3840*2);
  bf16* Wg    = (bf16*)alloc((size_t)768*1536*2);
  bf16* Wcat2 = (bf16*)alloc((size_t)768*2304*2);
  float* bslot = (float*)alloc(768*4);
  float* bcls  = (float*)alloc(768*4);
  size_t fixedOff = off;

  // pick largest batch chunk that fits in ws
  const size_t perBatch = (size_t)N_R*H_D*4      /* X  */
                        + (size_t)N_R*H_D*4      /* U  */
                        + (size_t)N_R*3840*2     /* Xcat */
                        + (size_t)N_R*1536*2;    /* Gin  */
  int chunkB = 512;
  while (chunkB > 64 && fixedOff + perBatch*chunkB + 65536 > ws_size) chunkB >>= 1;

  const int rows = chunkB * N_R;
  float* X   = (float*)alloc((size_t)rows*H_D*4);
  float* U   = (float*)alloc((size_t)rows*H_D*4);
  bf16* Xcat = (bf16*)alloc((size_t)rows*3840*2);
  bf16* Gin  = (bf16*)alloc((size_t)rows*1536*2);

  prep_norm_k<<<512, 64, 0, stream>>>(a_cur, a_slot, a_last, a_dom,
                                      Acr, Acc, Asl, Alr, Alc, Adm);
  {
    int tot = 768*3840 + 768*1536 + 768*2304 + 768;
    prep_weights_k<<<(tot+255)/256, 256, 0, stream>>>(W_r, b_r, W_s, b_s, W_g,
                                                      Wcat, Wg, Wcat2, bslot, bcls);
  }

  for (int b0 = 0; b0 < 512; b0 += chunkB) {
    prep_state_k<<<rows*3, 256, 0, stream>>>(slots, cls, X, Xcat, Gin, b0, rows);
    // ---- layer 1 (full: slots + cls) ----
    aggregate1_k<<<chunkB, 768, 0, stream>>>(X, Xcat, Acr, Acc, Asl, Alr, Alc, Adm, b0);
    gemm_k<3840,1><<<(rows/128)*6, 256, 0, stream>>>(Xcat, Wcat, U, Gin, bslot, bcls, b_g, X);
    gemm_k<1536,2><<<(rows/128)*6, 256, 0, stream>>>(Gin,  Wg,   U, Gin, bslot, bcls, b_g, X);
    // ---- layer 2 (cls rows only; slots outputs are never used) ----
    const int rows2 = chunkB * C_D;
    aggregate2_k<<<chunkB, 768, 0, stream>>>(X, Xcat, Gin, Acc, Alc, b0);
    gemm_k<2304,3><<<(rows2/128)*6, 256, 0, stream>>>(Xcat, Wcat2, U, Gin, bslot, bcls, b_g, X);
    gemm_k<1536,4><<<(rows2/128)*6, 256, 0, stream>>>(Gin,  Wg,    U, Gin, bslot, bcls, b_g, X);
    out_copy_k<<<chunkB*45, 256, 0, stream>>>(X, out, b0, chunkB);
  }
}

// Round 2
// 977.989 us; speedup vs baseline: 1.0141x; 1.0141x over previous
//
#include <hip/hip_runtime.h>
#include <hip/hip_bf16.h>
#include <cstdint>
#include <cstddef>

typedef __hip_bfloat16 bf16;
typedef __bf16 bf16x8 __attribute__((ext_vector_type(8)));
typedef float f32x4 __attribute__((ext_vector_type(4)));

#define S_D 30
#define C_D 16
#define N_R 46        // S_D + C_D rows per batch
#define H_D 768
#define EPS_F 1e-5f

// ------------------------------------------------------------------
// prep: normalize adjacency matrices once (they are layer-invariant)
// ------------------------------------------------------------------
__global__ __launch_bounds__(64) void prep_norm_k(
    const float* __restrict__ a_cur, const float* __restrict__ a_slot,
    const float* __restrict__ a_last, const float* __restrict__ a_dom,
    float* __restrict__ Acr, float* __restrict__ Acc, float* __restrict__ Asl,
    float* __restrict__ Alr, float* __restrict__ Alc, float* __restrict__ Adm)
{
  int b = blockIdx.x, t = threadIdx.x;
  const float* ac  = a_cur  + b*S_D*C_D;
  const float* as_ = a_slot + b*S_D*S_D;
  const float* al  = a_last + b*S_D*C_D;
  const float* ad  = a_dom  + b*S_D*S_D;
  if (t < S_D) {
    float s = 0; for (int c=0;c<C_D;c++) s += ac[t*C_D+c];
    float inv = 1.f/(s+EPS_F);
    for (int c=0;c<C_D;c++) Acr[b*S_D*C_D + t*C_D+c] = ac[t*C_D+c]*inv;
    s = 0; for (int c=0;c<C_D;c++) s += al[t*C_D+c];
    inv = 1.f/(s+EPS_F);
    for (int c=0;c<C_D;c++) Alr[b*S_D*C_D + t*C_D+c] = al[t*C_D+c]*inv;
    s = 0; for (int j=0;j<S_D;j++) s += as_[t*S_D+j];
    inv = 1.f/(s+EPS_F);
    for (int j=0;j<S_D;j++) Asl[b*S_D*S_D + t*S_D+j] = as_[t*S_D+j]*inv;
    s = 0; for (int j=0;j<S_D;j++) s += ad[t*S_D+j];
    inv = 1.f/(s+EPS_F);
    for (int j=0;j<S_D;j++) Adm[b*S_D*S_D + t*S_D+j] = ad[t*S_D+j]*inv;
  } else if (t < S_D + C_D) {
    int c = t - S_D;
    float s = 0; for (int j=0;j<S_D;j++) s += ac[j*C_D+c];
    float inv = 1.f/(s+EPS_F);
    for (int j=0;j<S_D;j++) Acc[b*S_D*C_D + j*C_D+c] = ac[j*C_D+c]*inv;
    s = 0; for (int j=0;j<S_D;j++) s += al[j*C_D+c];
    inv = 1.f/(s+EPS_F);
    for (int j=0;j<S_D;j++) Alc[b*S_D*C_D + j*C_D+c] = al[j*C_D+c]*inv;
  }
}

// ------------------------------------------------------------------
// prep: bf16 transposed weight concats + folded biases
// ------------------------------------------------------------------
__global__ __launch_bounds__(256) void prep_weights_k(
    const float* __restrict__ W_r, const float* __restrict__ b_r,
    const float* __restrict__ W_s, const float* __restrict__ b_s,
    const float* __restrict__ W_g,
    bf16* __restrict__ Wcat, bf16* __restrict__ Wg, bf16* __restrict__ Wcat2,
    float* __restrict__ bslot, float* __restrict__ bcls)
{
  int id = blockIdx.x*256 + threadIdx.x;
  const int n1 = 768*3840, n2 = 768*1536, n3 = 768*2304;
  if (id < n1) {
    int n = id / 3840, k = id % 3840, seg = k / 768, kk = k % 768;
    float w = (seg == 0) ? W_s[kk*768 + n] : W_r[((size_t)(seg-1)*768 + kk)*768 + n];
    Wcat[id] = __float2bfloat16(w);
  } else if (id < n1 + n2) {
    int j = id - n1; int n = j / 1536, k = j % 1536;
    Wg[j] = __float2bfloat16(W_g[(size_t)k*768 + n]);
  } else if (id < n1 + n2 + n3) {
    int j = id - n1 - n2; int n = j / 2304, k = j % 2304, seg = k / 768, kk = k % 768;
    float w = (seg == 0) ? W_s[kk*768 + n]
            : (seg == 1 ? W_r[(size_t)kk*768 + n] : W_r[((size_t)2*768 + kk)*768 + n]);
    Wcat2[j] = __float2bfloat16(w);
  } else if (id < n1 + n2 + n3 + 768) {
    int n = id - n1 - n2 - n3;
    bslot[n] = b_s[n] + b_r[n] + b_r[768+n] + b_r[2*768+n] + b_r[3*768+n];
    bcls[n]  = b_s[n] + b_r[n] + b_r[2*768+n];
  }
}

// ------------------------------------------------------------------
// fused init + layer-1 aggregation: one block per batch, 768 threads.
// Reads slots/cls from the original inputs, writes X (f32 state),
// Xcat seg0 + aggregate segs 1..4, and Gin right half. Coefs are
// wave-uniform loads -> s_load; the x column lives in registers.
// ------------------------------------------------------------------
__global__ __launch_bounds__(768) void fused_agg1_k(
    const float* __restrict__ slots, const float* __restrict__ cls,
    float* __restrict__ X, bf16* __restrict__ Xcat, bf16* __restrict__ Gin,
    const float* __restrict__ Acr, const float* __restrict__ Acc,
    const float* __restrict__ Asl, const float* __restrict__ Alr,
    const float* __restrict__ Alc, const float* __restrict__ Adm, int b0)
{
  int lb = blockIdx.x, b = b0 + lb, h = threadIdx.x;
  float xs[S_D], xc[C_D];
  #pragma unroll
  for (int s = 0; s < S_D; ++s) xs[s] = slots[((size_t)b*S_D + s)*768 + h];
  #pragma unroll
  for (int c = 0; c < C_D; ++c) xc[c] = cls[((size_t)b*C_D + c)*768 + h];

  float* Xb = X + (size_t)lb*N_R*768 + h;
  bf16*  Gb = Gin + (size_t)lb*N_R*1536 + 768 + h;
  bf16*  Xb16 = Xcat + (size_t)lb*N_R*3840 + h;
  #pragma unroll
  for (int s = 0; s < S_D; ++s) {
    Xb[s*768] = xs[s];
    bf16 bv = __float2bfloat16(xs[s]);
    Gb[(size_t)s*1536] = bv;
    Xb16[(size_t)s*3840] = bv;
  }
  #pragma unroll
  for (int c = 0; c < C_D; ++c) {
    Xb[(S_D+c)*768] = xc[c];
    bf16 bv = __float2bfloat16(xc[c]);
    Gb[(size_t)(S_D+c)*1536] = bv;
    Xb16[(size_t)(S_D+c)*3840] = bv;
  }

  const float* acr  = Acr + b*480;
  const float* acc_ = Acc + b*480;
  const float* alr  = Alr + b*480;
  const float* alc  = Alc + b*480;
  const float* asl  = Asl + b*900;
  const float* adm  = Adm + b*900;
  const bf16 z = __float2bfloat16(0.f);
  #pragma unroll 1
  for (int s = 0; s < S_D; ++s) {
    float a1 = 0, a2 = 0, a3 = 0, a4 = 0;
    #pragma unroll
    for (int c = 0; c < C_D; ++c) { a1 += acr[s*C_D + c]*xc[c]; a3 += alr[s*C_D + c]*xc[c]; }
    #pragma unroll
    for (int t = 0; t < S_D; ++t) { a2 += asl[s*S_D + t]*xs[t]; a4 += adm[s*S_D + t]*xs[t]; }
    bf16* row = Xb16 + (size_t)s*3840;
    row[768]  = __float2bfloat16(a1);
    row[1536] = __float2bfloat16(a2);
    row[2304] = __float2bfloat16(a3);
    row[3072] = __float2bfloat16(a4);
  }
  #pragma unroll 1
  for (int c = 0; c < C_D; ++c) {
    float a1 = 0, a3 = 0;
    #pragma unroll
    for (int s = 0; s < S_D; ++s) { a1 += acc_[s*C_D + c]*xs[s]; a3 += alc[s*C_D + c]*xs[s]; }
    bf16* row = Xb16 + (size_t)(S_D + c)*3840;
    row[768]  = __float2bfloat16(a1);
    row[1536] = z;
    row[2304] = __float2bfloat16(a3);
    row[3072] = z;
  }
}

// ------------------------------------------------------------------
// layer-2 aggregation (cls rows only): Xcat2 [chunkB*16, 2304]
// ------------------------------------------------------------------
__global__ __launch_bounds__(768) void aggregate2_k(
    const float* __restrict__ X, bf16* __restrict__ Xcat2, bf16* __restrict__ Gin2,
    const float* __restrict__ Acc, const float* __restrict__ Alc, int b0)
{
  int lb = blockIdx.x, b = b0 + lb, h = threadIdx.x;
  const float* Xb = X + (size_t)lb*N_R*768;
  float xs[S_D];
  #pragma unroll
  for (int s = 0; s < S_D; ++s) xs[s] = Xb[s*768 + h];
  const float* acc_ = Acc + b*480;
  const float* alc  = Alc + b*480;
  #pragma unroll 1
  for (int c = 0; c < C_D; ++c) {
    float v = Xb[(S_D + c)*768 + h];
    float a1 = 0, a3 = 0;
    #pragma unroll
    for (int s = 0; s < S_D; ++s) { a1 += acc_[s*C_D + c]*xs[s]; a3 += alc[s*C_D + c]*xs[s]; }
    size_t r2 = (size_t)lb*C_D + c;
    bf16* row = Xcat2 + r2*2304 + h;
    row[0]    = __float2bfloat16(v);
    row[768]  = __float2bfloat16(a1);
    row[1536] = __float2bfloat16(a3);
    Gin2[r2*1536 + 768 + h] = __float2bfloat16(v);
  }
}

// ------------------------------------------------------------------
// MFMA GEMM: C[M x 768] = A[M x K] @ Bt[768 x K]^T, 128x128 tile, BK=64,
// double-buffered LDS with prefetch (T3 minimum 2-phase), bijective
// XCD-chunked block swizzle (T1).
// EPI 1: proj layer1  -> U f32 + Gin[:, :768] bf16, bias by row type
// EPI 2: gate layer1  -> sigmoid + residual update -> X
// EPI 3: proj layer2  -> U + Gin left, bias_cls
// EPI 4: gate layer2  -> final cls -> written straight to out
// ------------------------------------------------------------------
template<int K, int EPI>
__global__ __launch_bounds__(256) void gemm_k(
    const bf16* __restrict__ A, const bf16* __restrict__ Bt,
    float* __restrict__ U, bf16* __restrict__ Gin,
    const float* __restrict__ bias_slot, const float* __restrict__ bias_cls,
    const float* __restrict__ bg, float* __restrict__ X,
    float* __restrict__ out, int b0)
{
  __shared__ __align__(16) bf16 As[2][128*64];
  __shared__ __align__(16) bf16 Bs[2][128*64];
  const int tid  = threadIdx.x;
  const int lane = tid & 63;
  const int wave = tid >> 6;
  const int wm = wave >> 1, wn = wave & 1;

  // T1: bijective XCD-chunked swizzle (m204): consecutive new-ids land on
  // one XCD so the 6 bn-blocks sharing an A-tile share that XCD's L2.
  const int nwg = gridDim.x;
  const int q = nwg >> 3, r = nwg & 7;
  const int xcd = blockIdx.x & 7, idx = blockIdx.x >> 3;
  const int wg = (xcd < r ? xcd*(q+1) : r*(q+1) + (xcd-r)*q) + idx;
  const int bm = wg / 6, bn = wg % 6;

  const bf16* Ag = A  + (size_t)bm*128*K + (size_t)(tid>>3)*K + (tid&7)*8;
  const bf16* Bg = Bt + (size_t)bn*128*K + (size_t)(tid>>3)*K + (tid&7)*8;
  const int ldsw = (wave*8)*64;

  f32x4 acc[4][4] = {};
  const int NT = K/64;

  auto stage = [&](int buf, int kt) {
    #pragma unroll
    for (int p = 0; p < 4; ++p) {
      __builtin_amdgcn_global_load_lds(
        (const __attribute__((address_space(1))) void*)(Ag + (size_t)(p*32)*K + kt),
        (__attribute__((address_space(3))) void*)(&As[buf][ldsw + p*32*64]), 16, 0, 0);
      __builtin_amdgcn_global_load_lds(
        (const __attribute__((address_space(1))) void*)(Bg + (size_t)(p*32)*K + kt),
        (__attribute__((address_space(3))) void*)(&Bs[buf][ldsw + p*32*64]), 16, 0, 0);
    }
  };

  stage(0, 0);
  __syncthreads();     // drain prologue loads (vmcnt(0)+barrier)
  int cur = 0;
  #pragma unroll 1
  for (int t = 0; t < NT; ++t) {
    if (t + 1 < NT) stage(cur ^ 1, (t + 1)*64);   // prefetch flies under compute
    const bf16* Asb = As[cur];
    const bf16* Bsb = Bs[cur];
    #pragma unroll
    for (int ks = 0; ks < 64; ks += 32) {
      bf16x8 af[4], bfv[4];
      #pragma unroll
      for (int i = 0; i < 4; ++i) {
        int m = wm*64 + i*16 + (lane & 15);
        af[i]  = *(const bf16x8*)&Asb[m*64 + ks + ((lane>>4)<<3)];
        int n = wn*64 + i*16 + (lane & 15);
        bfv[i] = *(const bf16x8*)&Bsb[n*64 + ks + ((lane>>4)<<3)];
      }
      #pragma unroll
      for (int i = 0; i < 4; ++i)
        #pragma unroll
        for (int j = 0; j < 4; ++j)
          acc[i][j] = __builtin_amdgcn_mfma_f32_16x16x32_bf16(af[i], bfv[j], acc[i][j], 0, 0, 0);
    }
    __syncthreads();   // drains vmcnt(0): prefetch landed; barrier: reads done
    cur ^= 1;
  }

  const int rbase = bm*128 + wm*64 + ((lane>>4)<<2);
  const int cbase = bn*128 + wn*64 + (lane & 15);
  #pragma unroll
  for (int i = 0; i < 4; ++i) {
    #pragma unroll
    for (int j = 0; j < 4; ++j) {
      const int col = cbase + j*16;
      #pragma unroll
      for (int r2 = 0; r2 < 4; ++r2) {
        const int row = rbase + i*16 + r2;
        float v = acc[i][j][r2];
        if constexpr (EPI == 1) {
          int rb = row % N_R;
          v += (rb < S_D ? bias_slot[col] : bias_cls[col]);
          U[(size_t)row*H_D + col] = v;
          Gin[(size_t)row*1536 + col] = __float2bfloat16(v);
        } else if constexpr (EPI == 3) {
          v += bias_cls[col];
          U[(size_t)row*H_D + col] = v;
          Gin[(size_t)row*1536 + col] = __float2bfloat16(v);
        } else if constexpr (EPI == 2) {
          v += bg[col];
          float g = 1.f/(1.f + __expf(-v));
          float u  = U[(size_t)row*H_D + col];
          float xo = X[(size_t)row*H_D + col];
          X[(size_t)row*H_D + col] = fmaxf(u, 0.f)*g + xo*(1.f - g);
        } else { // EPI == 4: final cls gate -> write straight to out
          v += bg[col];
          float g = 1.f/(1.f + __expf(-v));
          float u = U[(size_t)row*H_D + col];
          int lb2 = row >> 4, c = row & 15;
          if (c >= 1) {
            float xo = X[((size_t)lb2*N_R + S_D + c)*H_D + col];
            out[((size_t)(b0 + lb2)*15 + (c - 1))*H_D + col] =
                fmaxf(u, 0.f)*g + xo*(1.f - g);
          }
        }
      }
    }
  }
}

// ------------------------------------------------------------------
extern "C" void kernel_launch(void* const* d_in, const int* in_sizes, int n_in,
                              void* d_out, int out_size, void* d_ws, size_t ws_size,
                              hipStream_t stream)
{
  const float* slots  = (const float*)d_in[0];
  const float* cls    = (const float*)d_in[1];
  const float* a_cur  = (const float*)d_in[2];
  const float* a_slot = (const float*)d_in[3];
  const float* a_last = (const float*)d_in[4];
  const float* a_dom  = (const float*)d_in[5];
  const float* W_r    = (const float*)d_in[6];
  const float* b_r    = (const float*)d_in[7];
  const float* W_s    = (const float*)d_in[8];
  const float* b_s    = (const float*)d_in[9];
  const float* W_g    = (const float*)d_in[10];
  const float* b_g    = (const float*)d_in[11];
  float* out = (float*)d_out;

  char* base = (char*)d_ws;
  size_t off = 0;
  auto alloc = [&](size_t bytes) -> void* {
    void* r = base + off;
    off = (off + bytes + 255) & ~(size_t)255;
    return r;
  };

  float* Acr = (float*)alloc((size_t)512*480*4);
  float* Acc = (float*)alloc((size_t)512*480*4);
  float* Alr = (float*)alloc((size_t)512*480*4);
  float* Alc = (float*)alloc((size_t)512*480*4);
  float* Asl = (float*)alloc((size_t)512*900*4);
  float* Adm = (float*)alloc((size_t)512*900*4);
  bf16* Wcat  = (bf16*)alloc((size_t)768*3840*2);
  bf16* Wg    = (bf16*)alloc((size_t)768*1536*2);
  bf16* Wcat2 = (bf16*)alloc((size_t)768*2304*2);
  float* bslot = (float*)alloc(768*4);
  float* bcls  = (float*)alloc(768*4);
  size_t fixedOff = off;

  const size_t perBatch = (size_t)N_R*H_D*4      /* X  */
                        + (size_t)N_R*H_D*4      /* U  */
                        + (size_t)N_R*3840*2     /* Xcat */
                        + (size_t)N_R*1536*2;    /* Gin  */
  int chunkB = 512;
  while (chunkB > 64 && fixedOff + perBatch*chunkB + 65536 > ws_size) chunkB >>= 1;

  const int rows = chunkB * N_R;
  float* X   = (float*)alloc((size_t)rows*H_D*4);
  float* U   = (float*)alloc((size_t)rows*H_D*4);
  bf16* Xcat = (bf16*)alloc((size_t)rows*3840*2);
  bf16* Gin  = (bf16*)alloc((size_t)rows*1536*2);

  prep_norm_k<<<512, 64, 0, stream>>>(a_cur, a_slot, a_last, a_dom,
                                      Acr, Acc, Asl, Alr, Alc, Adm);
  {
    int tot = 768*3840 + 768*1536 + 768*2304 + 768;
    prep_weights_k<<<(tot+255)/256, 256, 0, stream>>>(W_r, b_r, W_s, b_s, W_g,
                                                      Wcat, Wg, Wcat2, bslot, bcls);
  }

  for (int b0 = 0; b0 < 512; b0 += chunkB) {
    // ---- layer 1 (full: slots + cls) ----
    fused_agg1_k<<<chunkB, 768, 0, stream>>>(slots, cls, X, Xcat, Gin,
                                             Acr, Acc, Asl, Alr, Alc, Adm, b0);
    gemm_k<3840,1><<<(rows/128)*6, 256, 0, stream>>>(Xcat, Wcat, U, Gin, bslot, bcls, b_g, X, out, b0);
    gemm_k<1536,2><<<(rows/128)*6, 256, 0, stream>>>(Gin,  Wg,   U, Gin, bslot, bcls, b_g, X, out, b0);
    // ---- layer 2 (cls rows only; slot outputs are never used) ----
    const int rows2 = chunkB * C_D;
    aggregate2_k<<<chunkB, 768, 0, stream>>>(X, Xcat, Gin, Acc, Alc, b0);
    gemm_k<2304,3><<<(rows2/128)*6, 256, 0, stream>>>(Xcat, Wcat2, U, Gin, bslot, bcls, b_g, X, out, b0);
    gemm_k<1536,4><<<(rows2/128)*6, 256, 0, stream>>>(Gin,  Wg,    U, Gin, bslot, bcls, b_g, X, out, b0);
  }
}

// Round 3
// 846.579 us; speedup vs baseline: 1.1715x; 1.1552x over previous
//
#include <hip/hip_runtime.h>
#include <hip/hip_bf16.h>
#include <cstdint>
#include <cstddef>

typedef __hip_bfloat16 bf16;
typedef __bf16 bf16x8 __attribute__((ext_vector_type(8)));
typedef float f32x4 __attribute__((ext_vector_type(4)));

#define S_D 30
#define C_D 16
#define N_R 46        // S_D + C_D rows per batch
#define H_D 768
#define EPS_F 1e-5f

// ------------------------------------------------------------------
// prep: normalize adjacency matrices once (they are layer-invariant)
// ------------------------------------------------------------------
__global__ __launch_bounds__(64) void prep_norm_k(
    const float* __restrict__ a_cur, const float* __restrict__ a_slot,
    const float* __restrict__ a_last, const float* __restrict__ a_dom,
    float* __restrict__ Acr, float* __restrict__ Acc, float* __restrict__ Asl,
    float* __restrict__ Alr, float* __restrict__ Alc, float* __restrict__ Adm)
{
  int b = blockIdx.x, t = threadIdx.x;
  const float* ac  = a_cur  + b*S_D*C_D;
  const float* as_ = a_slot + b*S_D*S_D;
  const float* al  = a_last + b*S_D*C_D;
  const float* ad  = a_dom  + b*S_D*S_D;
  if (t < S_D) {
    float s = 0; for (int c=0;c<C_D;c++) s += ac[t*C_D+c];
    float inv = 1.f/(s+EPS_F);
    for (int c=0;c<C_D;c++) Acr[b*S_D*C_D + t*C_D+c] = ac[t*C_D+c]*inv;
    s = 0; for (int c=0;c<C_D;c++) s += al[t*C_D+c];
    inv = 1.f/(s+EPS_F);
    for (int c=0;c<C_D;c++) Alr[b*S_D*C_D + t*C_D+c] = al[t*C_D+c]*inv;
    s = 0; for (int j=0;j<S_D;j++) s += as_[t*S_D+j];
    inv = 1.f/(s+EPS_F);
    for (int j=0;j<S_D;j++) Asl[b*S_D*S_D + t*S_D+j] = as_[t*S_D+j]*inv;
    s = 0; for (int j=0;j<S_D;j++) s += ad[t*S_D+j];
    inv = 1.f/(s+EPS_F);
    for (int j=0;j<S_D;j++) Adm[b*S_D*S_D + t*S_D+j] = ad[t*S_D+j]*inv;
  } else if (t < S_D + C_D) {
    int c = t - S_D;
    float s = 0; for (int j=0;j<S_D;j++) s += ac[j*C_D+c];
    float inv = 1.f/(s+EPS_F);
    for (int j=0;j<S_D;j++) Acc[b*S_D*C_D + j*C_D+c] = ac[j*C_D+c]*inv;
    s = 0; for (int j=0;j<S_D;j++) s += al[j*C_D+c];
    inv = 1.f/(s+EPS_F);
    for (int j=0;j<S_D;j++) Alc[b*S_D*C_D + j*C_D+c] = al[j*C_D+c]*inv;
  }
}

// ------------------------------------------------------------------
// prep: bf16 transposed weight concats + folded biases
// ------------------------------------------------------------------
__global__ __launch_bounds__(256) void prep_weights_k(
    const float* __restrict__ W_r, const float* __restrict__ b_r,
    const float* __restrict__ W_s, const float* __restrict__ b_s,
    const float* __restrict__ W_g,
    bf16* __restrict__ Wcat, bf16* __restrict__ Wg, bf16* __restrict__ Wcat2,
    float* __restrict__ bslot, float* __restrict__ bcls)
{
  int id = blockIdx.x*256 + threadIdx.x;
  const int n1 = 768*3840, n2 = 768*1536, n3 = 768*2304;
  if (id < n1) {
    int n = id / 3840, k = id % 3840, seg = k / 768, kk = k % 768;
    float w = (seg == 0) ? W_s[kk*768 + n] : W_r[((size_t)(seg-1)*768 + kk)*768 + n];
    Wcat[id] = __float2bfloat16(w);
  } else if (id < n1 + n2) {
    int j = id - n1; int n = j / 1536, k = j % 1536;
    Wg[j] = __float2bfloat16(W_g[(size_t)k*768 + n]);
  } else if (id < n1 + n2 + n3) {
    int j = id - n1 - n2; int n = j / 2304, k = j % 2304, seg = k / 768, kk = k % 768;
    float w = (seg == 0) ? W_s[kk*768 + n]
            : (seg == 1 ? W_r[(size_t)kk*768 + n] : W_r[((size_t)2*768 + kk)*768 + n]);
    Wcat2[j] = __float2bfloat16(w);
  } else if (id < n1 + n2 + n3 + 768) {
    int n = id - n1 - n2 - n3;
    bslot[n] = b_s[n] + b_r[n] + b_r[768+n] + b_r[2*768+n] + b_r[3*768+n];
    bcls[n]  = b_s[n] + b_r[n] + b_r[2*768+n];
  }
}

// ------------------------------------------------------------------
// fused init + layer-1 aggregation: one block per batch, 768 threads.
// Writes X (f32 state), Gin right half (bf16 x), and Zagg (4 aggregate
// segments, stride 3072). Coefs are wave-uniform loads -> s_load.
// ------------------------------------------------------------------
__global__ __launch_bounds__(768) void fused_agg1_k(
    const float* __restrict__ slots, const float* __restrict__ cls,
    float* __restrict__ X, bf16* __restrict__ Zagg, bf16* __restrict__ Gin,
    const float* __restrict__ Acr, const float* __restrict__ Acc,
    const float* __restrict__ Asl, const float* __restrict__ Alr,
    const float* __restrict__ Alc, const float* __restrict__ Adm, int b0)
{
  int lb = blockIdx.x, b = b0 + lb, h = threadIdx.x;
  float xs[S_D], xc[C_D];
  #pragma unroll
  for (int s = 0; s < S_D; ++s) xs[s] = slots[((size_t)b*S_D + s)*768 + h];
  #pragma unroll
  for (int c = 0; c < C_D; ++c) xc[c] = cls[((size_t)b*C_D + c)*768 + h];

  float* Xb = X + (size_t)lb*N_R*768 + h;
  bf16*  Gb = Gin + (size_t)lb*N_R*1536 + 768 + h;
  #pragma unroll
  for (int s = 0; s < S_D; ++s) {
    Xb[s*768] = xs[s];
    Gb[(size_t)s*1536] = __float2bfloat16(xs[s]);
  }
  #pragma unroll
  for (int c = 0; c < C_D; ++c) {
    Xb[(S_D+c)*768] = xc[c];
    Gb[(size_t)(S_D+c)*1536] = __float2bfloat16(xc[c]);
  }

  const float* acr  = Acr + b*480;
  const float* acc_ = Acc + b*480;
  const float* alr  = Alr + b*480;
  const float* alc  = Alc + b*480;
  const float* asl  = Asl + b*900;
  const float* adm  = Adm + b*900;
  bf16* Zb = Zagg + (size_t)lb*N_R*3072 + h;
  const bf16 z = __float2bfloat16(0.f);
  #pragma unroll 1
  for (int s = 0; s < S_D; ++s) {
    float a1 = 0, a2 = 0, a3 = 0, a4 = 0;
    #pragma unroll
    for (int c = 0; c < C_D; ++c) { a1 += acr[s*C_D + c]*xc[c]; a3 += alr[s*C_D + c]*xc[c]; }
    #pragma unroll
    for (int t = 0; t < S_D; ++t) { a2 += asl[s*S_D + t]*xs[t]; a4 += adm[s*S_D + t]*xs[t]; }
    bf16* row = Zb + (size_t)s*3072;
    row[0]    = __float2bfloat16(a1);
    row[768]  = __float2bfloat16(a2);
    row[1536] = __float2bfloat16(a3);
    row[2304] = __float2bfloat16(a4);
  }
  #pragma unroll 1
  for (int c = 0; c < C_D; ++c) {
    float a1 = 0, a3 = 0;
    #pragma unroll
    for (int s = 0; s < S_D; ++s) { a1 += acc_[s*C_D + c]*xs[s]; a3 += alc[s*C_D + c]*xs[s]; }
    bf16* row = Zb + (size_t)(S_D + c)*3072;
    row[0]    = __float2bfloat16(a1);
    row[768]  = z;
    row[1536] = __float2bfloat16(a3);
    row[2304] = z;
  }
}

// ------------------------------------------------------------------
// layer-2 aggregation (cls rows only). Writes Gin2 right half (new cls
// x, bf16) and Zagg2 (2 segments, stride 1536). X holds layer-1 output.
// ------------------------------------------------------------------
__global__ __launch_bounds__(768) void aggregate2_k(
    const float* __restrict__ X, bf16* __restrict__ Zagg2, bf16* __restrict__ Gin2,
    const float* __restrict__ Acc, const float* __restrict__ Alc, int b0)
{
  int lb = blockIdx.x, b = b0 + lb, h = threadIdx.x;
  const float* Xb = X + (size_t)lb*N_R*768;
  float xs[S_D];
  #pragma unroll
  for (int s = 0; s < S_D; ++s) xs[s] = Xb[s*768 + h];
  const float* acc_ = Acc + b*480;
  const float* alc  = Alc + b*480;
  #pragma unroll 1
  for (int c = 0; c < C_D; ++c) {
    float v = Xb[(S_D + c)*768 + h];
    float a1 = 0, a3 = 0;
    #pragma unroll
    for (int s = 0; s < S_D; ++s) { a1 += acc_[s*C_D + c]*xs[s]; a3 += alc[s*C_D + c]*xs[s]; }
    size_t r2 = (size_t)lb*C_D + c;
    Zagg2[r2*1536 + h]       = __float2bfloat16(a1);
    Zagg2[r2*1536 + 768 + h] = __float2bfloat16(a3);
    Gin2[r2*1536 + 768 + h]  = __float2bfloat16(v);
  }
}

// ------------------------------------------------------------------
// MFMA GEMM: C[M x 768] = A[M x K] @ Bt[768 x K]^T, 128x128 tile, BK=64,
// single-buffer LDS (32 KB -> more blocks/CU), T1 bijective XCD swizzle,
// T2 both-sides XOR swizzle: pre-swizzled global source slot + linear
// global_load_lds dest + XOR'd ds_read (rule #21).
// A streams from up to two sources: cols [0,SK) from A0 (stride LDA0),
// cols [SK,K) from A1 (stride LDA1) -- avoids materializing the concat.
// EPI 1: proj layer1 -> Gin left (bf16), bias by row type
// EPI 2: gate layer1 -> sigmoid + residual -> X (u read from Gin left)
// EPI 3: proj layer2 -> Gin2 left, bias_cls
// EPI 4: gate layer2 -> final cls -> written straight to out
// ------------------------------------------------------------------
template<int K, int EPI, int LDA0, int LDA1, int SK>
__global__ __launch_bounds__(256) void gemm_k(
    const bf16* __restrict__ A0, const bf16* __restrict__ A1,
    const bf16* __restrict__ Bt, bf16* __restrict__ G,
    const float* __restrict__ bias_slot, const float* __restrict__ bias_cls,
    const float* __restrict__ bg, float* __restrict__ X,
    float* __restrict__ out, int b0)
{
  __shared__ __align__(16) bf16 As[128*64];
  __shared__ __align__(16) bf16 Bs[128*64];
  const int tid  = threadIdx.x;
  const int lane = tid & 63;
  const int wave = tid >> 6;
  const int wm = wave >> 1, wn = wave & 1;

  // T1: bijective XCD-chunked swizzle (m204)
  const int nwg = gridDim.x;
  const int q = nwg >> 3, r = nwg & 7;
  const int xcd = blockIdx.x & 7, idx = blockIdx.x >> 3;
  const int wg = (xcd < r ? xcd*(q+1) : r*(q+1) + (xcd-r)*q) + idx;
  const int bm = wg / 6, bn = wg % 6;

  // T2 write side: pre-swizzled global source slot, linear LDS dest.
  const int swz = (((tid & 7) ^ ((tid >> 3) & 7))) << 3;   // elements
  const bf16* Ag0 = A0 + (size_t)(bm*128 + (tid>>3))*LDA0 + swz;
  const bf16* Ag1 = A1 + (size_t)(bm*128 + (tid>>3))*LDA1 + swz;
  const bf16* Bg  = Bt + (size_t)(bn*128 + (tid>>3))*K    + swz;
  bf16* Asw = &As[(wave*8)*64];
  bf16* Bsw = &Bs[(wave*8)*64];

  f32x4 acc[4][4] = {};

  #pragma unroll 1
  for (int kt = 0; kt < K; kt += 64) {
    #pragma unroll
    for (int p = 0; p < 4; ++p) {
      const bf16* asrc = (kt < SK) ? (Ag0 + (size_t)(p*32)*LDA0 + kt)
                                   : (Ag1 + (size_t)(p*32)*LDA1 + (kt - SK));
      __builtin_amdgcn_global_load_lds(
        (const __attribute__((address_space(1))) void*)asrc,
        (__attribute__((address_space(3))) void*)(Asw + p*32*64), 16, 0, 0);
      __builtin_amdgcn_global_load_lds(
        (const __attribute__((address_space(1))) void*)(Bg + (size_t)(p*32)*K + kt),
        (__attribute__((address_space(3))) void*)(Bsw + p*32*64), 16, 0, 0);
    }
    __syncthreads();
    #pragma unroll
    for (int ks = 0; ks < 64; ks += 32) {
      bf16x8 af[4], bfv[4];
      // T2 read side: logical slot j = ks/8 + lane/16, physical = j ^ (row&7)
      const int sa = ((((ks >> 3) + (lane >> 4)) ^ (lane & 7))) << 3;
      #pragma unroll
      for (int i = 0; i < 4; ++i) {
        int m = wm*64 + i*16 + (lane & 15);
        af[i]  = *(const bf16x8*)&As[m*64 + sa];
        int n = wn*64 + i*16 + (lane & 15);
        bfv[i] = *(const bf16x8*)&Bs[n*64 + sa];
      }
      #pragma unroll
      for (int i = 0; i < 4; ++i)
        #pragma unroll
        for (int j = 0; j < 4; ++j)
          acc[i][j] = __builtin_amdgcn_mfma_f32_16x16x32_bf16(af[i], bfv[j], acc[i][j], 0, 0, 0);
    }
    __syncthreads();
  }

  const int rbase = bm*128 + wm*64 + ((lane>>4)<<2);
  const int cbase = bn*128 + wn*64 + (lane & 15);
  #pragma unroll
  for (int i = 0; i < 4; ++i) {
    #pragma unroll
    for (int j = 0; j < 4; ++j) {
      const int col = cbase + j*16;
      #pragma unroll
      for (int r2 = 0; r2 < 4; ++r2) {
        const int row = rbase + i*16 + r2;
        float v = acc[i][j][r2];
        if constexpr (EPI == 1) {
          int rb = row % N_R;
          v += (rb < S_D ? bias_slot[col] : bias_cls[col]);
          G[(size_t)row*1536 + col] = __float2bfloat16(v);
        } else if constexpr (EPI == 3) {
          v += bias_cls[col];
          G[(size_t)row*1536 + col] = __float2bfloat16(v);
        } else if constexpr (EPI == 2) {
          v += bg[col];
          float g = 1.f/(1.f + __expf(-v));
          float u  = __bfloat162float(G[(size_t)row*1536 + col]);
          float xo = X[(size_t)row*H_D + col];
          X[(size_t)row*H_D + col] = fmaxf(u, 0.f)*g + xo*(1.f - g);
        } else { // EPI == 4: final cls gate -> write straight to out
          v += bg[col];
          float g = 1.f/(1.f + __expf(-v));
          float u = __bfloat162float(G[(size_t)row*1536 + col]);
          int lb2 = row >> 4, c = row & 15;
          if (c >= 1) {
            float xo = X[((size_t)lb2*N_R + S_D + c)*H_D + col];
            out[((size_t)(b0 + lb2)*15 + (c - 1))*H_D + col] =
                fmaxf(u, 0.f)*g + xo*(1.f - g);
          }
        }
      }
    }
  }
}

// ------------------------------------------------------------------
extern "C" void kernel_launch(void* const* d_in, const int* in_sizes, int n_in,
                              void* d_out, int out_size, void* d_ws, size_t ws_size,
                              hipStream_t stream)
{
  const float* slots  = (const float*)d_in[0];
  const float* cls    = (const float*)d_in[1];
  const float* a_cur  = (const float*)d_in[2];
  const float* a_slot = (const float*)d_in[3];
  const float* a_last = (const float*)d_in[4];
  const float* a_dom  = (const float*)d_in[5];
  const float* W_r    = (const float*)d_in[6];
  const float* b_r    = (const float*)d_in[7];
  const float* W_s    = (const float*)d_in[8];
  const float* b_s    = (const float*)d_in[9];
  const float* W_g    = (const float*)d_in[10];
  const float* b_g    = (const float*)d_in[11];
  float* out = (float*)d_out;

  char* base = (char*)d_ws;
  size_t off = 0;
  auto alloc = [&](size_t bytes) -> void* {
    void* r = base + off;
    off = (off + bytes + 255) & ~(size_t)255;
    return r;
  };

  float* Acr = (float*)alloc((size_t)512*480*4);
  float* Acc = (float*)alloc((size_t)512*480*4);
  float* Alr = (float*)alloc((size_t)512*480*4);
  float* Alc = (float*)alloc((size_t)512*480*4);
  float* Asl = (float*)alloc((size_t)512*900*4);
  float* Adm = (float*)alloc((size_t)512*900*4);
  bf16* Wcat  = (bf16*)alloc((size_t)768*3840*2);
  bf16* Wg    = (bf16*)alloc((size_t)768*1536*2);
  bf16* Wcat2 = (bf16*)alloc((size_t)768*2304*2);
  float* bslot = (float*)alloc(768*4);
  float* bcls  = (float*)alloc(768*4);
  size_t fixedOff = off;

  // per-batch footprint: X f32 + Zagg bf16 (46x3072) + Gin bf16 (46x1536)
  const size_t perBatch = (size_t)N_R*H_D*4
                        + (size_t)N_R*3072*2
                        + (size_t)N_R*1536*2;
  int chunkB = 512;
  while (chunkB > 64 && fixedOff + perBatch*chunkB + 65536 > ws_size) chunkB >>= 1;

  const int rows = chunkB * N_R;
  float* X    = (float*)alloc((size_t)rows*H_D*4);
  bf16* Zagg  = (bf16*)alloc((size_t)rows*3072*2);
  bf16* Gin   = (bf16*)alloc((size_t)rows*1536*2);

  prep_norm_k<<<512, 64, 0, stream>>>(a_cur, a_slot, a_last, a_dom,
                                      Acr, Acc, Asl, Alr, Alc, Adm);
  {
    int tot = 768*3840 + 768*1536 + 768*2304 + 768;
    prep_weights_k<<<(tot+255)/256, 256, 0, stream>>>(W_r, b_r, W_s, b_s, W_g,
                                                      Wcat, Wg, Wcat2, bslot, bcls);
  }

  for (int b0 = 0; b0 < 512; b0 += chunkB) {
    // ---- layer 1 (full: slots + cls) ----
    fused_agg1_k<<<chunkB, 768, 0, stream>>>(slots, cls, X, Zagg, Gin,
                                             Acr, Acc, Asl, Alr, Alc, Adm, b0);
    // proj: A = [x (Gin right) | Zagg], K=3840
    gemm_k<3840,1,1536,3072,768><<<(rows/128)*6, 256, 0, stream>>>(
        Gin + 768, Zagg, Wcat, Gin, bslot, bcls, b_g, X, out, b0);
    // gate: A = Gin = [u | x], K=1536
    gemm_k<1536,2,1536,1536,1536><<<(rows/128)*6, 256, 0, stream>>>(
        Gin, Gin, Wg, Gin, bslot, bcls, b_g, X, out, b0);
    // ---- layer 2 (cls rows only; slot outputs are never used) ----
    const int rows2 = chunkB * C_D;
    aggregate2_k<<<chunkB, 768, 0, stream>>>(X, Zagg, Gin, Acc, Alc, b0);
    // proj: A = [cls x (Gin right) | Zagg2], K=2304
    gemm_k<2304,3,1536,1536,768><<<(rows2/128)*6, 256, 0, stream>>>(
        Gin + 768, Zagg, Wcat2, Gin, bslot, bcls, b_g, X, out, b0);
    // gate: A = Gin2 = [u | x], K=1536
    gemm_k<1536,4,1536,1536,1536><<<(rows2/128)*6, 256, 0, stream>>>(
        Gin, Gin, Wg, Gin, bslot, bcls, b_g, X, out, b0);
  }
}